// Round 13
// baseline (206.332 us; speedup 1.0000x reference)
//
#include <hip/hip_runtime.h>
#include <stdint.h>

#define N_NODES 8192
#define MAXD 128            // max distinct degree (Binomial(262144,1/8192), mean ~32; 128 tail-safe)
#define NG 128

// workspace layout
#define OFF_NNZ    (8u * 1024 * 1024)          // bitmap is [0, 8 MiB)
#define OFF_COLS   (OFF_NNZ + 32u * 1024)      // ushort cols, 2 MiB
#define ZERO_BYTES OFF_COLS                    // zero bitmap + nnz only
#define OFF_BUF1   (OFF_COLS + 2u * 1024 * 1024)
#define OFF_BUF2   (OFF_BUF1 + 2u * 1024 * 1024)

// RULES (R6-R12 hard-won):
//  1. Cross-block data handoff ONLY across kernel boundaries.
//  2. NO in-gather dinv_j (reading nnz[j] per neighbor in SpMM) — failed 3/3
//     (R9/R10/R12) at ~2e-3; prescale-by-dinv_j via mm1 passes (R4/R11).

__device__ __forceinline__ float bc(float v, int k) {  // wave broadcast lane k
    return __int_as_float(__builtin_amdgcn_readlane(__float_as_int(v), k));
}

// ---- K1: fused dedup + CSR (R4/R11-proven verbatim) ----
__global__ void edge_csr_kernel(const int* __restrict__ ei, int E,
                                unsigned int* __restrict__ bitmap,
                                int* __restrict__ nnz,
                                unsigned short* __restrict__ cols) {
    int k = blockIdx.x * blockDim.x + threadIdx.x;
    if (k >= E) return;
    int r = ei[k];
    int c = ei[E + k];
    unsigned int bit = 1u << (c & 31);
    unsigned int old = atomicOr(&bitmap[(r << 8) + (c >> 5)], bit);
    if (!(old & bit)) {                      // set semantics: first setter appends
        int pos = atomicAdd(&nnz[r], 1);
        cols[r * MAXD + pos] = (unsigned short)c;
    }
}

// ---- K2: layer-1 dense prescale (R4/R11-proven verbatim) ----
// bufA[i,f] = dinv_i * sum_k x[i,k] * th1[k,f]   (K=7)
__global__ void mm1_kernel(const float* __restrict__ x, const float* __restrict__ th,
                           const int* __restrict__ nnz, float* __restrict__ out) {
    __shared__ float sT[7 * 64];
    __shared__ float sX[4 * 7];
    int row0 = blockIdx.x << 2;
    for (int t = threadIdx.x; t < 7 * 64; t += 256) sT[t] = th[t];
    if (threadIdx.x < 28) sX[threadIdx.x] = x[row0 * 7 + threadIdx.x];
    __syncthreads();
    int r = threadIdx.x >> 6, f = threadIdx.x & 63;
    float acc = 0.f;
    #pragma unroll
    for (int k = 0; k < 7; ++k) acc = fmaf(sX[r * 7 + k], sT[(k << 6) + f], acc);
    int row = row0 + r;
    float dinv = 1.0f / sqrtf((float)nnz[row] + 1.0f);
    out[(row << 6) + f] = acc * dinv;
}

// ---- K3/K4: fused SpMM + relu + dense theta (R4/R11-proven verbatim) ----
// h[i,:]  = relu( dinv_i * ( ht[i,:] + sum_j ht[j,:] ) )      (ht prescaled by dinv_j)
// out[i,f] = dinv_i * sum_k h[i,k] * th[k,f]
__global__ void spmm_theta_kernel(const unsigned short* __restrict__ cols,
                                  const int* __restrict__ nnz,
                                  const float* __restrict__ ht,
                                  const float* __restrict__ th,
                                  float* __restrict__ out) {
    __shared__ float sT[64 * 64];
    #pragma unroll
    for (int t = 0; t < 16; ++t) sT[threadIdx.x + (t << 8)] = th[threadIdx.x + (t << 8)];
    __syncthreads();

    int row  = (blockIdx.x << 2) + (threadIdx.x >> 6);
    int lane = threadIdx.x & 63;
    int n = nnz[row];
    float dinv = 1.0f / sqrtf((float)n + 1.0f);
    const unsigned short* crow = cols + row * MAXD;
    int j0 = crow[lane];
    int j1 = crow[64 + lane];
    float acc = ht[(row << 6) + lane];              // eye term
    int n0 = n < 64 ? n : 64;
    for (int t = 0; t < n0; ++t) {
        int j = __builtin_amdgcn_readlane(j0, t);   // SGPR neighbor id
        acc += ht[(j << 6) + lane];                 // 256B coalesced row gather, L2-hit
    }
    for (int t = 64; t < n; ++t) {
        int j = __builtin_amdgcn_readlane(j1, t - 64);
        acc += ht[(j << 6) + lane];
    }
    float h = fmaxf(acc * dinv, 0.f);               // relu'd hidden value, feature=lane
    float acc2 = 0.f;
    #pragma unroll
    for (int k = 0; k < 64; ++k)
        acc2 = fmaf(bc(h, k), sT[(k << 6) + lane], acc2);
    out[(row << 6) + lane] = acc2 * dinv;
}

// ---- K5: fused layer-3 SpMM + per-graph mean-pool + relu + W,b ----
// THE ONE CHANGE THIS ROUND. batch is SORTED: one block per graph; its row
// range [lo,hi) via binary search. Block-local reduction only — no atomics,
// no cross-block communication; all inputs written by PRIOR dispatches.
__device__ __forceinline__ int lbound(const int* __restrict__ a, int n, int v) {
    int lo = 0, hi = n;
    while (lo < hi) { int m = (lo + hi) >> 1; if (a[m] < v) lo = m + 1; else hi = m; }
    return lo;
}

__global__ void __launch_bounds__(256)
spmm_pool_final_kernel(const unsigned short* __restrict__ cols,
                       const int* __restrict__ nnz,
                       const float* __restrict__ ht,      // prescaled layer-3 input
                       const int* __restrict__ batch,
                       const float* __restrict__ W, const float* __restrict__ bia,
                       float* __restrict__ out) {
    __shared__ float sP[4 * 64];
    const int g    = blockIdx.x;                   // 128 graphs
    const int lane = threadIdx.x & 63;
    const int wave = threadIdx.x >> 6;
    const int lo = lbound(batch, N_NODES, g);
    const int hi = lbound(batch, N_NODES, g + 1);

    float sum = 0.f;
    for (int row = lo + wave; row < hi; row += 4) {
        int n = nnz[row];
        float dinv = 1.0f / sqrtf((float)n + 1.0f);
        const unsigned short* crow = cols + row * MAXD;
        int j0 = crow[lane];
        int j1 = crow[64 + lane];
        float acc = ht[(row << 6) + lane];
        int n0 = n < 64 ? n : 64;
        for (int t = 0; t < n0; ++t) {
            int j = __builtin_amdgcn_readlane(j0, t);
            acc += ht[(j << 6) + lane];
        }
        for (int t = 64; t < n; ++t) {
            int j = __builtin_amdgcn_readlane(j1, t - 64);
            acc += ht[(j << 6) + lane];
        }
        sum += acc * dinv;                         // h3[row][lane]
    }
    sP[(wave << 6) + lane] = sum;
    __syncthreads();
    if (wave == 0) {
        float s = sP[lane] + sP[64 + lane] + sP[128 + lane] + sP[192 + lane];
        int cntg = hi - lo; if (cntg < 1) cntg = 1;
        float p = fmaxf(s / (float)cntg, 0.f);     // relu(mean), feature = lane
        float w0 = p * W[(lane << 1) + 0];
        float w1 = p * W[(lane << 1) + 1];
        #pragma unroll
        for (int off = 32; off >= 1; off >>= 1) {
            w0 += __shfl_xor(w0, off, 64);
            w1 += __shfl_xor(w1, off, 64);
        }
        if (lane == 0) {
            out[(g << 1) + 0] = bia[0] + w0;
            out[(g << 1) + 1] = bia[1] + w1;
        }
    }
}

extern "C" void kernel_launch(void* const* d_in, const int* in_sizes, int n_in,
                              void* d_out, int out_size, void* d_ws, size_t ws_size,
                              hipStream_t stream) {
    const float* x     = (const float*)d_in[0];
    const int*   ei    = (const int*)d_in[1];
    const int*   batch = (const int*)d_in[2];
    const float* th1   = (const float*)d_in[3];
    const float* th2   = (const float*)d_in[4];
    const float* th3   = (const float*)d_in[5];
    const float* W     = (const float*)d_in[6];
    const float* b     = (const float*)d_in[7];
    float* out = (float*)d_out;
    int E = in_sizes[1] / 2;

    char* ws = (char*)d_ws;
    unsigned int*   bitmap = (unsigned int*)ws;
    int*            nnz    = (int*)(ws + OFF_NNZ);
    unsigned short* cols   = (unsigned short*)(ws + OFF_COLS);
    float*          buf1   = (float*)(ws + OFF_BUF1);
    float*          buf2   = (float*)(ws + OFF_BUF2);

    hipMemsetAsync(ws, 0, ZERO_BYTES, stream);   // bitmap + nnz

    edge_csr_kernel<<<(E + 255) / 256, 256, 0, stream>>>(ei, E, bitmap, nnz, cols);
    mm1_kernel<<<N_NODES / 4, 256, 0, stream>>>(x, th1, nnz, buf1);
    spmm_theta_kernel<<<N_NODES / 4, 256, 0, stream>>>(cols, nnz, buf1, th2, buf2);
    spmm_theta_kernel<<<N_NODES / 4, 256, 0, stream>>>(cols, nnz, buf2, th3, buf1);
    spmm_pool_final_kernel<<<NG, 256, 0, stream>>>(cols, nnz, buf1, batch, W, b, out);
}

// Round 14
// 96.844 us; speedup vs baseline: 2.1306x; 2.1306x over previous
//
#include <hip/hip_runtime.h>
#include <stdint.h>

#define N_NODES 8192
#define MAXD 128            // max distinct degree (Binomial(262144,1/8192), mean ~32; 128 tail-safe)
#define NG 128

// workspace layout
#define OFF_NNZ    (8u * 1024 * 1024)          // bitmap is [0, 8 MiB)
#define OFF_COLS   (OFF_NNZ + 32u * 1024)      // ushort cols, 2 MiB
#define ZERO_BYTES OFF_COLS                    // zero bitmap + nnz only
#define OFF_BUF1   (OFF_COLS + 2u * 1024 * 1024)
#define OFF_BUF2   (OFF_BUF1 + 2u * 1024 * 1024)
#define OFF_BUF3   (OFF_BUF2 + 2u * 1024 * 1024)

// RULES (R6-R13 hard-won):
//  1. Cross-block data handoff ONLY across kernel boundaries (coop/ticket: 4/4 fail).
//  2. Do NOT perturb the proven per-row arithmetic (in-gather dinv_j: 3/3 fail at
//     ~2e-3 = one bf16 ulp; prescale-by-dinv_j via mm1: passes at absmax 0.0).
//  3. Avoid hot atomic pooling (R11's spmm_pool+final pair ~41 us); block-local
//     reduction over sorted batch is proven exact (R13) — just keep SpMM at full
//     occupancy (R13's fused K5 at 512 waves was 138 us latency-bound).

__device__ __forceinline__ float bc(float v, int k) {  // wave broadcast lane k
    return __int_as_float(__builtin_amdgcn_readlane(__float_as_int(v), k));
}

// ---- K1: fused dedup + CSR (R4/R11-proven verbatim) ----
__global__ void edge_csr_kernel(const int* __restrict__ ei, int E,
                                unsigned int* __restrict__ bitmap,
                                int* __restrict__ nnz,
                                unsigned short* __restrict__ cols) {
    int k = blockIdx.x * blockDim.x + threadIdx.x;
    if (k >= E) return;
    int r = ei[k];
    int c = ei[E + k];
    unsigned int bit = 1u << (c & 31);
    unsigned int old = atomicOr(&bitmap[(r << 8) + (c >> 5)], bit);
    if (!(old & bit)) {                      // set semantics: first setter appends
        int pos = atomicAdd(&nnz[r], 1);
        cols[r * MAXD + pos] = (unsigned short)c;
    }
}

// ---- K2: layer-1 dense prescale (R4/R11-proven verbatim) ----
__global__ void mm1_kernel(const float* __restrict__ x, const float* __restrict__ th,
                           const int* __restrict__ nnz, float* __restrict__ out) {
    __shared__ float sT[7 * 64];
    __shared__ float sX[4 * 7];
    int row0 = blockIdx.x << 2;
    for (int t = threadIdx.x; t < 7 * 64; t += 256) sT[t] = th[t];
    if (threadIdx.x < 28) sX[threadIdx.x] = x[row0 * 7 + threadIdx.x];
    __syncthreads();
    int r = threadIdx.x >> 6, f = threadIdx.x & 63;
    float acc = 0.f;
    #pragma unroll
    for (int k = 0; k < 7; ++k) acc = fmaf(sX[r * 7 + k], sT[(k << 6) + f], acc);
    int row = row0 + r;
    float dinv = 1.0f / sqrtf((float)nnz[row] + 1.0f);
    out[(row << 6) + f] = acc * dinv;
}

// ---- K3/K4: fused SpMM + relu + dense theta (R4/R11-proven verbatim) ----
__global__ void spmm_theta_kernel(const unsigned short* __restrict__ cols,
                                  const int* __restrict__ nnz,
                                  const float* __restrict__ ht,
                                  const float* __restrict__ th,
                                  float* __restrict__ out) {
    __shared__ float sT[64 * 64];
    #pragma unroll
    for (int t = 0; t < 16; ++t) sT[threadIdx.x + (t << 8)] = th[threadIdx.x + (t << 8)];
    __syncthreads();

    int row  = (blockIdx.x << 2) + (threadIdx.x >> 6);
    int lane = threadIdx.x & 63;
    int n = nnz[row];
    float dinv = 1.0f / sqrtf((float)n + 1.0f);
    const unsigned short* crow = cols + row * MAXD;
    int j0 = crow[lane];
    int j1 = crow[64 + lane];
    float acc = ht[(row << 6) + lane];              // eye term
    int n0 = n < 64 ? n : 64;
    for (int t = 0; t < n0; ++t) {
        int j = __builtin_amdgcn_readlane(j0, t);   // SGPR neighbor id
        acc += ht[(j << 6) + lane];                 // 256B coalesced row gather, L2-hit
    }
    for (int t = 64; t < n; ++t) {
        int j = __builtin_amdgcn_readlane(j1, t - 64);
        acc += ht[(j << 6) + lane];
    }
    float h = fmaxf(acc * dinv, 0.f);               // relu'd hidden value, feature=lane
    float acc2 = 0.f;
    #pragma unroll
    for (int k = 0; k < 64; ++k)
        acc2 = fmaf(bc(h, k), sT[(k << 6) + lane], acc2);
    out[(row << 6) + lane] = acc2 * dinv;
}

// ---- K5: layer-3 SpMM at FULL occupancy (2048 blocks), no theta, no atomics ----
// h3[i,:] = dinv_i * ( ht[i,:] + sum_j ht[j,:] )   (ht prescaled by dinv_j)
__global__ void __launch_bounds__(256)
spmm3_kernel(const unsigned short* __restrict__ cols,
             const int* __restrict__ nnz,
             const float* __restrict__ ht,
             float* __restrict__ out) {
    int row  = (blockIdx.x << 2) + (threadIdx.x >> 6);
    int lane = threadIdx.x & 63;
    int n = nnz[row];
    float dinv = 1.0f / sqrtf((float)n + 1.0f);
    const unsigned short* crow = cols + row * MAXD;
    int j0 = crow[lane];
    int j1 = crow[64 + lane];
    float acc = ht[(row << 6) + lane];
    int n0 = n < 64 ? n : 64;
    for (int t = 0; t < n0; ++t) {
        int j = __builtin_amdgcn_readlane(j0, t);
        acc += ht[(j << 6) + lane];
    }
    for (int t = 64; t < n; ++t) {
        int j = __builtin_amdgcn_readlane(j1, t - 64);
        acc += ht[(j << 6) + lane];
    }
    out[(row << 6) + lane] = acc * dinv;            // h3 row, feature = lane
}

// ---- K6: per-graph mean-pool + relu + W,b — reads h3 rows only (no gathers) ----
// batch SORTED: one block per graph; rows [lo,hi) via binary search; block-local
// LDS reduce (same partial order as R13's proven K5). No cross-block traffic.
__device__ __forceinline__ int lbound(const int* __restrict__ a, int n, int v) {
    int lo = 0, hi = n;
    while (lo < hi) { int m = (lo + hi) >> 1; if (a[m] < v) lo = m + 1; else hi = m; }
    return lo;
}

__global__ void __launch_bounds__(256)
pool_final_kernel(const float* __restrict__ h3,
                  const int* __restrict__ batch,
                  const float* __restrict__ W, const float* __restrict__ bia,
                  float* __restrict__ out) {
    __shared__ float sP[4 * 64];
    const int g    = blockIdx.x;                   // 128 graphs
    const int lane = threadIdx.x & 63;
    const int wave = threadIdx.x >> 6;
    const int lo = lbound(batch, N_NODES, g);
    const int hi = lbound(batch, N_NODES, g + 1);

    float sum = 0.f;
    for (int row = lo + wave; row < hi; row += 4)
        sum += h3[(row << 6) + lane];               // coalesced 256B row reads
    sP[(wave << 6) + lane] = sum;
    __syncthreads();
    if (wave == 0) {
        float s = sP[lane] + sP[64 + lane] + sP[128 + lane] + sP[192 + lane];
        int cntg = hi - lo; if (cntg < 1) cntg = 1;
        float p = fmaxf(s / (float)cntg, 0.f);      // relu(mean), feature = lane
        float w0 = p * W[(lane << 1) + 0];
        float w1 = p * W[(lane << 1) + 1];
        #pragma unroll
        for (int off = 32; off >= 1; off >>= 1) {
            w0 += __shfl_xor(w0, off, 64);
            w1 += __shfl_xor(w1, off, 64);
        }
        if (lane == 0) {
            out[(g << 1) + 0] = bia[0] + w0;
            out[(g << 1) + 1] = bia[1] + w1;
        }
    }
}

extern "C" void kernel_launch(void* const* d_in, const int* in_sizes, int n_in,
                              void* d_out, int out_size, void* d_ws, size_t ws_size,
                              hipStream_t stream) {
    const float* x     = (const float*)d_in[0];
    const int*   ei    = (const int*)d_in[1];
    const int*   batch = (const int*)d_in[2];
    const float* th1   = (const float*)d_in[3];
    const float* th2   = (const float*)d_in[4];
    const float* th3   = (const float*)d_in[5];
    const float* W     = (const float*)d_in[6];
    const float* b     = (const float*)d_in[7];
    float* out = (float*)d_out;
    int E = in_sizes[1] / 2;

    char* ws = (char*)d_ws;
    unsigned int*   bitmap = (unsigned int*)ws;
    int*            nnz    = (int*)(ws + OFF_NNZ);
    unsigned short* cols   = (unsigned short*)(ws + OFF_COLS);
    float*          buf1   = (float*)(ws + OFF_BUF1);
    float*          buf2   = (float*)(ws + OFF_BUF2);
    float*          buf3   = (float*)(ws + OFF_BUF3);

    hipMemsetAsync(ws, 0, ZERO_BYTES, stream);   // bitmap + nnz

    edge_csr_kernel<<<(E + 255) / 256, 256, 0, stream>>>(ei, E, bitmap, nnz, cols);
    mm1_kernel<<<N_NODES / 4, 256, 0, stream>>>(x, th1, nnz, buf1);
    spmm_theta_kernel<<<N_NODES / 4, 256, 0, stream>>>(cols, nnz, buf1, th2, buf2);
    spmm_theta_kernel<<<N_NODES / 4, 256, 0, stream>>>(cols, nnz, buf2, th3, buf1);
    spmm3_kernel<<<N_NODES / 4, 256, 0, stream>>>(cols, nnz, buf1, buf3);
    pool_final_kernel<<<NG, 256, 0, stream>>>(buf3, batch, W, b, out);
}

// Round 15
// 79.152 us; speedup vs baseline: 2.6068x; 1.2235x over previous
//
#include <hip/hip_runtime.h>
#include <stdint.h>

#define N_NODES 8192
#define MAXD 128            // max distinct degree (Binomial(262144,1/8192), mean ~32; 128 tail-safe)
#define NG 128

// workspace layout
#define OFF_NNZ    (8u * 1024 * 1024)          // bitmap is [0, 8 MiB)
#define OFF_COLS   (OFF_NNZ + 32u * 1024)      // ushort cols, 2 MiB
#define ZERO_BYTES OFF_COLS                    // zero bitmap + nnz only
#define OFF_BUF1   (OFF_COLS + 2u * 1024 * 1024)
#define OFF_BUF2   (OFF_BUF1 + 2u * 1024 * 1024)
#define OFF_BUF3   (OFF_BUF2 + 2u * 1024 * 1024)

// RULES (R6-R14 hard-won):
//  1. Cross-block data handoff ONLY across kernel boundaries (coop/ticket: 4/4 fail).
//  2. Do NOT perturb the per-row arithmetic ORDER/values (in-gather dinv_j: 3/3 fail
//     at ~one-bf16-ulp; prescale via mm1 passes at absmax 0.0). Unrolling that
//     preserves the add sequence is safe.
//  3. No hot atomic pooling; block-local pool over sorted batch (R13/R14-proven).
//  4. Gather SpMMs are latency-bound (R13: VALUBusy 2.5%) -> ILP unroll.

__device__ __forceinline__ float bc(float v, int k) {  // wave broadcast lane k
    return __int_as_float(__builtin_amdgcn_readlane(__float_as_int(v), k));
}

// ---- K1: fused dedup + CSR (R4/R11-proven verbatim) ----
__global__ void edge_csr_kernel(const int* __restrict__ ei, int E,
                                unsigned int* __restrict__ bitmap,
                                int* __restrict__ nnz,
                                unsigned short* __restrict__ cols) {
    int k = blockIdx.x * blockDim.x + threadIdx.x;
    if (k >= E) return;
    int r = ei[k];
    int c = ei[E + k];
    unsigned int bit = 1u << (c & 31);
    unsigned int old = atomicOr(&bitmap[(r << 8) + (c >> 5)], bit);
    if (!(old & bit)) {                      // set semantics: first setter appends
        int pos = atomicAdd(&nnz[r], 1);
        cols[r * MAXD + pos] = (unsigned short)c;
    }
}

// ---- K2: layer-1 dense prescale (R4/R11-proven verbatim) ----
__global__ void mm1_kernel(const float* __restrict__ x, const float* __restrict__ th,
                           const int* __restrict__ nnz, float* __restrict__ out) {
    __shared__ float sT[7 * 64];
    __shared__ float sX[4 * 7];
    int row0 = blockIdx.x << 2;
    for (int t = threadIdx.x; t < 7 * 64; t += 256) sT[t] = th[t];
    if (threadIdx.x < 28) sX[threadIdx.x] = x[row0 * 7 + threadIdx.x];
    __syncthreads();
    int r = threadIdx.x >> 6, f = threadIdx.x & 63;
    float acc = 0.f;
    #pragma unroll
    for (int k = 0; k < 7; ++k) acc = fmaf(sX[r * 7 + k], sT[(k << 6) + f], acc);
    int row = row0 + r;
    float dinv = 1.0f / sqrtf((float)nnz[row] + 1.0f);
    out[(row << 6) + f] = acc * dinv;
}

// 8-deep ILP gather, ADD ORDER IDENTICAL to the serial loop (k, k+1, ..., k+7)
__device__ __forceinline__ float gather_rows(const float* __restrict__ ht,
                                             int j0, int j1, int n, int lane,
                                             float acc) {
    int n0 = n < 64 ? n : 64;
    int k = 0;
    for (; k + 8 <= n0; k += 8) {
        int ja = __builtin_amdgcn_readlane(j0, k + 0);
        int jb = __builtin_amdgcn_readlane(j0, k + 1);
        int jc = __builtin_amdgcn_readlane(j0, k + 2);
        int jd = __builtin_amdgcn_readlane(j0, k + 3);
        int je = __builtin_amdgcn_readlane(j0, k + 4);
        int jf = __builtin_amdgcn_readlane(j0, k + 5);
        int jg = __builtin_amdgcn_readlane(j0, k + 6);
        int jh = __builtin_amdgcn_readlane(j0, k + 7);
        float va = ht[(ja << 6) + lane];
        float vb = ht[(jb << 6) + lane];
        float vc = ht[(jc << 6) + lane];
        float vd = ht[(jd << 6) + lane];
        float ve = ht[(je << 6) + lane];
        float vf = ht[(jf << 6) + lane];
        float vg = ht[(jg << 6) + lane];
        float vh = ht[(jh << 6) + lane];
        acc += va; acc += vb; acc += vc; acc += vd;
        acc += ve; acc += vf; acc += vg; acc += vh;
    }
    for (; k < n0; ++k) {
        int j = __builtin_amdgcn_readlane(j0, k);
        acc += ht[(j << 6) + lane];
    }
    for (int t = 64; t < n; ++t) {                  // rare tail (deg > 64)
        int j = __builtin_amdgcn_readlane(j1, t - 64);
        acc += ht[(j << 6) + lane];
    }
    return acc;
}

// ---- K3/K4: fused SpMM + relu + dense theta (R14 + ILP unroll) ----
__global__ void __launch_bounds__(256)
spmm_theta_kernel(const unsigned short* __restrict__ cols,
                  const int* __restrict__ nnz,
                  const float* __restrict__ ht,
                  const float* __restrict__ th,
                  float* __restrict__ out) {
    __shared__ float sT[64 * 64];
    #pragma unroll
    for (int t = 0; t < 16; ++t) sT[threadIdx.x + (t << 8)] = th[threadIdx.x + (t << 8)];
    __syncthreads();

    int row  = (blockIdx.x << 2) + (threadIdx.x >> 6);
    int lane = threadIdx.x & 63;
    int n = nnz[row];
    float dinv = 1.0f / sqrtf((float)n + 1.0f);
    const unsigned short* crow = cols + row * MAXD;
    int j0 = crow[lane];
    int j1 = crow[64 + lane];
    float acc = gather_rows(ht, j0, j1, n, lane, ht[(row << 6) + lane]);
    float h = fmaxf(acc * dinv, 0.f);               // relu'd hidden value, feature=lane
    float acc2 = 0.f;
    #pragma unroll
    for (int k = 0; k < 64; ++k)
        acc2 = fmaf(bc(h, k), sT[(k << 6) + lane], acc2);
    out[(row << 6) + lane] = acc2 * dinv;
}

// ---- K5: layer-3 SpMM, full occupancy, no theta (R14 + ILP unroll) ----
__global__ void __launch_bounds__(256)
spmm3_kernel(const unsigned short* __restrict__ cols,
             const int* __restrict__ nnz,
             const float* __restrict__ ht,
             float* __restrict__ out) {
    int row  = (blockIdx.x << 2) + (threadIdx.x >> 6);
    int lane = threadIdx.x & 63;
    int n = nnz[row];
    float dinv = 1.0f / sqrtf((float)n + 1.0f);
    const unsigned short* crow = cols + row * MAXD;
    int j0 = crow[lane];
    int j1 = crow[64 + lane];
    float acc = gather_rows(ht, j0, j1, n, lane, ht[(row << 6) + lane]);
    out[(row << 6) + lane] = acc * dinv;            // h3 row, feature = lane
}

// ---- K6: per-graph mean-pool + relu + W,b (R14-proven verbatim) ----
__device__ __forceinline__ int lbound(const int* __restrict__ a, int n, int v) {
    int lo = 0, hi = n;
    while (lo < hi) { int m = (lo + hi) >> 1; if (a[m] < v) lo = m + 1; else hi = m; }
    return lo;
}

__global__ void __launch_bounds__(256)
pool_final_kernel(const float* __restrict__ h3,
                  const int* __restrict__ batch,
                  const float* __restrict__ W, const float* __restrict__ bia,
                  float* __restrict__ out) {
    __shared__ float sP[4 * 64];
    const int g    = blockIdx.x;                   // 128 graphs
    const int lane = threadIdx.x & 63;
    const int wave = threadIdx.x >> 6;
    const int lo = lbound(batch, N_NODES, g);
    const int hi = lbound(batch, N_NODES, g + 1);

    float sum = 0.f;
    for (int row = lo + wave; row < hi; row += 4)
        sum += h3[(row << 6) + lane];               // coalesced 256B row reads
    sP[(wave << 6) + lane] = sum;
    __syncthreads();
    if (wave == 0) {
        float s = sP[lane] + sP[64 + lane] + sP[128 + lane] + sP[192 + lane];
        int cntg = hi - lo; if (cntg < 1) cntg = 1;
        float p = fmaxf(s / (float)cntg, 0.f);      // relu(mean), feature = lane
        float w0 = p * W[(lane << 1) + 0];
        float w1 = p * W[(lane << 1) + 1];
        #pragma unroll
        for (int off = 32; off >= 1; off >>= 1) {
            w0 += __shfl_xor(w0, off, 64);
            w1 += __shfl_xor(w1, off, 64);
        }
        if (lane == 0) {
            out[(g << 1) + 0] = bia[0] + w0;
            out[(g << 1) + 1] = bia[1] + w1;
        }
    }
}

extern "C" void kernel_launch(void* const* d_in, const int* in_sizes, int n_in,
                              void* d_out, int out_size, void* d_ws, size_t ws_size,
                              hipStream_t stream) {
    const float* x     = (const float*)d_in[0];
    const int*   ei    = (const int*)d_in[1];
    const int*   batch = (const int*)d_in[2];
    const float* th1   = (const float*)d_in[3];
    const float* th2   = (const float*)d_in[4];
    const float* th3   = (const float*)d_in[5];
    const float* W     = (const float*)d_in[6];
    const float* b     = (const float*)d_in[7];
    float* out = (float*)d_out;
    int E = in_sizes[1] / 2;

    char* ws = (char*)d_ws;
    unsigned int*   bitmap = (unsigned int*)ws;
    int*            nnz    = (int*)(ws + OFF_NNZ);
    unsigned short* cols   = (unsigned short*)(ws + OFF_COLS);
    float*          buf1   = (float*)(ws + OFF_BUF1);
    float*          buf2   = (float*)(ws + OFF_BUF2);
    float*          buf3   = (float*)(ws + OFF_BUF3);

    hipMemsetAsync(ws, 0, ZERO_BYTES, stream);   // bitmap + nnz

    edge_csr_kernel<<<(E + 255) / 256, 256, 0, stream>>>(ei, E, bitmap, nnz, cols);
    mm1_kernel<<<N_NODES / 4, 256, 0, stream>>>(x, th1, nnz, buf1);
    spmm_theta_kernel<<<N_NODES / 4, 256, 0, stream>>>(cols, nnz, buf1, th2, buf2);
    spmm_theta_kernel<<<N_NODES / 4, 256, 0, stream>>>(cols, nnz, buf2, th3, buf1);
    spmm3_kernel<<<N_NODES / 4, 256, 0, stream>>>(cols, nnz, buf1, buf3);
    pool_final_kernel<<<NG, 256, 0, stream>>>(buf3, batch, W, b, out);
}

// Round 17
// 78.928 us; speedup vs baseline: 2.6142x; 1.0028x over previous
//
#include <hip/hip_runtime.h>
#include <stdint.h>

#define N_NODES 8192
#define MAXD 128            // max distinct degree (Binomial(262144,1/8192), mean ~32; 128 tail-safe)
#define NG 128

// workspace layout
#define OFF_NNZ    (8u * 1024 * 1024)          // bitmap is [0, 8 MiB)
#define OFF_COLS   (OFF_NNZ + 32u * 1024)      // ushort cols, 2 MiB
#define ZERO_BYTES OFF_COLS                    // zero bitmap + nnz only
#define OFF_BUF1   (OFF_COLS + 2u * 1024 * 1024)
#define OFF_BUF2   (OFF_BUF1 + 2u * 1024 * 1024)
#define OFF_BUF3   (OFF_BUF2 + 2u * 1024 * 1024)

// RULES (R6-R16, final):
//  1. Cross-block data handoff ONLY across kernel boundaries (coop/ticket: 4/4 fail).
//  2. BLACKLISTED: in-gather dinv_j in any form (fmaf, __fmul_rn) and edge+mm1
//     same-dispatch fusion — 5/5 failures (R9/R10/R12/R16, ~2e-3..NaN). Only the
//     mm1-prescale path passes (R4/R11/R13/R14/R15, absmax 0.0).
//  3. No hot atomic pooling; block-local pool over sorted batch (R13/R14-proven).
//  4. Gathers are latency-bound -> deep ILP with PRESERVED add order is safe
//     (R15: ILP-8 gave -17.7us). This round: ILP-16.

__device__ __forceinline__ float bc(float v, int k) {  // wave broadcast lane k
    return __int_as_float(__builtin_amdgcn_readlane(__float_as_int(v), k));
}

// ---- K1: fused dedup + CSR (R4/R11-proven verbatim) ----
__global__ void edge_csr_kernel(const int* __restrict__ ei, int E,
                                unsigned int* __restrict__ bitmap,
                                int* __restrict__ nnz,
                                unsigned short* __restrict__ cols) {
    int k = blockIdx.x * blockDim.x + threadIdx.x;
    if (k >= E) return;
    int r = ei[k];
    int c = ei[E + k];
    unsigned int bit = 1u << (c & 31);
    unsigned int old = atomicOr(&bitmap[(r << 8) + (c >> 5)], bit);
    if (!(old & bit)) {                      // set semantics: first setter appends
        int pos = atomicAdd(&nnz[r], 1);
        cols[r * MAXD + pos] = (unsigned short)c;
    }
}

// ---- K2: layer-1 dense prescale (R4/R11-proven verbatim) ----
__global__ void mm1_kernel(const float* __restrict__ x, const float* __restrict__ th,
                           const int* __restrict__ nnz, float* __restrict__ out) {
    __shared__ float sT[7 * 64];
    __shared__ float sX[4 * 7];
    int row0 = blockIdx.x << 2;
    for (int t = threadIdx.x; t < 7 * 64; t += 256) sT[t] = th[t];
    if (threadIdx.x < 28) sX[threadIdx.x] = x[row0 * 7 + threadIdx.x];
    __syncthreads();
    int r = threadIdx.x >> 6, f = threadIdx.x & 63;
    float acc = 0.f;
    #pragma unroll
    for (int k = 0; k < 7; ++k) acc = fmaf(sX[r * 7 + k], sT[(k << 6) + f], acc);
    int row = row0 + r;
    float dinv = 1.0f / sqrtf((float)nnz[row] + 1.0f);
    out[(row << 6) + f] = acc * dinv;
}

// 16-deep ILP gather, ADD ORDER IDENTICAL to the serial loop (k, k+1, ..., k+15)
__device__ __forceinline__ float gather_rows(const float* __restrict__ ht,
                                             int j0, int j1, int n, int lane,
                                             float acc) {
    int n0 = n < 64 ? n : 64;
    int k = 0;
    for (; k + 16 <= n0; k += 16) {
        int j[16];
        float v[16];
        #pragma unroll
        for (int u = 0; u < 16; ++u) j[u] = __builtin_amdgcn_readlane(j0, k + u);
        #pragma unroll
        for (int u = 0; u < 16; ++u) v[u] = ht[(j[u] << 6) + lane];
        #pragma unroll
        for (int u = 0; u < 16; ++u) acc += v[u];
    }
    for (; k + 8 <= n0; k += 8) {
        int j[8];
        float v[8];
        #pragma unroll
        for (int u = 0; u < 8; ++u) j[u] = __builtin_amdgcn_readlane(j0, k + u);
        #pragma unroll
        for (int u = 0; u < 8; ++u) v[u] = ht[(j[u] << 6) + lane];
        #pragma unroll
        for (int u = 0; u < 8; ++u) acc += v[u];
    }
    for (; k < n0; ++k) {
        int j = __builtin_amdgcn_readlane(j0, k);
        acc += ht[(j << 6) + lane];
    }
    for (int t = 64; t < n; ++t) {                  // rare tail (deg > 64)
        int j = __builtin_amdgcn_readlane(j1, t - 64);
        acc += ht[(j << 6) + lane];
    }
    return acc;
}

// ---- K3/K4: fused SpMM + relu + dense theta (R15 + ILP-16) ----
__global__ void __launch_bounds__(256)
spmm_theta_kernel(const unsigned short* __restrict__ cols,
                  const int* __restrict__ nnz,
                  const float* __restrict__ ht,
                  const float* __restrict__ th,
                  float* __restrict__ out) {
    __shared__ float sT[64 * 64];
    #pragma unroll
    for (int t = 0; t < 16; ++t) sT[threadIdx.x + (t << 8)] = th[threadIdx.x + (t << 8)];
    __syncthreads();

    int row  = (blockIdx.x << 2) + (threadIdx.x >> 6);
    int lane = threadIdx.x & 63;
    int n = nnz[row];
    float dinv = 1.0f / sqrtf((float)n + 1.0f);
    const unsigned short* crow = cols + row * MAXD;
    int j0 = crow[lane];
    int j1 = crow[64 + lane];
    float acc = gather_rows(ht, j0, j1, n, lane, ht[(row << 6) + lane]);
    float h = fmaxf(acc * dinv, 0.f);               // relu'd hidden value, feature=lane
    float acc2 = 0.f;
    #pragma unroll
    for (int k = 0; k < 64; ++k)
        acc2 = fmaf(bc(h, k), sT[(k << 6) + lane], acc2);
    out[(row << 6) + lane] = acc2 * dinv;
}

// ---- K5: layer-3 SpMM, full occupancy, no theta (R15 + ILP-16) ----
__global__ void __launch_bounds__(256)
spmm3_kernel(const unsigned short* __restrict__ cols,
             const int* __restrict__ nnz,
             const float* __restrict__ ht,
             float* __restrict__ out) {
    int row  = (blockIdx.x << 2) + (threadIdx.x >> 6);
    int lane = threadIdx.x & 63;
    int n = nnz[row];
    float dinv = 1.0f / sqrtf((float)n + 1.0f);
    const unsigned short* crow = cols + row * MAXD;
    int j0 = crow[lane];
    int j1 = crow[64 + lane];
    float acc = gather_rows(ht, j0, j1, n, lane, ht[(row << 6) + lane]);
    out[(row << 6) + lane] = acc * dinv;            // h3 row, feature = lane
}

// ---- K6: per-graph mean-pool + relu + W,b (R14-proven verbatim) ----
__device__ __forceinline__ int lbound(const int* __restrict__ a, int n, int v) {
    int lo = 0, hi = n;
    while (lo < hi) { int m = (lo + hi) >> 1; if (a[m] < v) lo = m + 1; else hi = m; }
    return lo;
}

__global__ void __launch_bounds__(256)
pool_final_kernel(const float* __restrict__ h3,
                  const int* __restrict__ batch,
                  const float* __restrict__ W, const float* __restrict__ bia,
                  float* __restrict__ out) {
    __shared__ float sP[4 * 64];
    const int g    = blockIdx.x;                   // 128 graphs
    const int lane = threadIdx.x & 63;
    const int wave = threadIdx.x >> 6;
    const int lo = lbound(batch, N_NODES, g);
    const int hi = lbound(batch, N_NODES, g + 1);

    float sum = 0.f;
    for (int row = lo + wave; row < hi; row += 4)
        sum += h3[(row << 6) + lane];               // coalesced 256B row reads
    sP[(wave << 6) + lane] = sum;
    __syncthreads();
    if (wave == 0) {
        float s = sP[lane] + sP[64 + lane] + sP[128 + lane] + sP[192 + lane];
        int cntg = hi - lo; if (cntg < 1) cntg = 1;
        float p = fmaxf(s / (float)cntg, 0.f);      // relu(mean), feature = lane
        float w0 = p * W[(lane << 1) + 0];
        float w1 = p * W[(lane << 1) + 1];
        #pragma unroll
        for (int off = 32; off >= 1; off >>= 1) {
            w0 += __shfl_xor(w0, off, 64);
            w1 += __shfl_xor(w1, off, 64);
        }
        if (lane == 0) {
            out[(g << 1) + 0] = bia[0] + w0;
            out[(g << 1) + 1] = bia[1] + w1;
        }
    }
}

extern "C" void kernel_launch(void* const* d_in, const int* in_sizes, int n_in,
                              void* d_out, int out_size, void* d_ws, size_t ws_size,
                              hipStream_t stream) {
    const float* x     = (const float*)d_in[0];
    const int*   ei    = (const int*)d_in[1];
    const int*   batch = (const int*)d_in[2];
    const float* th1   = (const float*)d_in[3];
    const float* th2   = (const float*)d_in[4];
    const float* th3   = (const float*)d_in[5];
    const float* W     = (const float*)d_in[6];
    const float* b     = (const float*)d_in[7];
    float* out = (float*)d_out;
    int E = in_sizes[1] / 2;

    char* ws = (char*)d_ws;
    unsigned int*   bitmap = (unsigned int*)ws;
    int*            nnz    = (int*)(ws + OFF_NNZ);
    unsigned short* cols   = (unsigned short*)(ws + OFF_COLS);
    float*          buf1   = (float*)(ws + OFF_BUF1);
    float*          buf2   = (float*)(ws + OFF_BUF2);
    float*          buf3   = (float*)(ws + OFF_BUF3);

    hipMemsetAsync(ws, 0, ZERO_BYTES, stream);   // bitmap + nnz

    edge_csr_kernel<<<(E + 255) / 256, 256, 0, stream>>>(ei, E, bitmap, nnz, cols);
    mm1_kernel<<<N_NODES / 4, 256, 0, stream>>>(x, th1, nnz, buf1);
    spmm_theta_kernel<<<N_NODES / 4, 256, 0, stream>>>(cols, nnz, buf1, th2, buf2);
    spmm_theta_kernel<<<N_NODES / 4, 256, 0, stream>>>(cols, nnz, buf2, th3, buf1);
    spmm3_kernel<<<N_NODES / 4, 256, 0, stream>>>(cols, nnz, buf1, buf3);
    pool_final_kernel<<<NG, 256, 0, stream>>>(buf3, batch, W, b, out);
}